// Round 2
// baseline (944.151 us; speedup 1.0000x reference)
//
#include <hip/hip_runtime.h>

#define T_LEN  1024
#define D_DIM  8
#define NWAVE  16          // waves per block = T/64
#define TSTEPS 1088        // padded local steps (17*64), t=1087 is an all-invalid step
#define RB     256         // ring buffer entries (power of 2)
#define BIGV   1e30f
#define EPSV   1e-6f

// wave-wide shift toward higher lanes: dst[n] = src[n-1] (lane0 keeps old, patched later)
__device__ __forceinline__ float dpp_shr1(float x) {
  int xi = __builtin_bit_cast(int, x);
  int r = __builtin_amdgcn_update_dpp(xi, xi, 0x138 /*wave_shr:1*/, 0xf, 0xf, false);
  return __builtin_bit_cast(float, r);
}

// ---------------------------------------------------------------------------
// Precompute dist[b][w][t][l] = ||obs[b, 64w+l, :] - mod[b, t-l, :] + eps||  (fp16)
// Layout matches the DTW read order exactly (coalesced 64 halfs per (w,t)).
// ---------------------------------------------------------------------------
__global__ __launch_bounds__(256)
void dist_kernel(const float* __restrict__ obs, const float* __restrict__ mod,
                 _Float16* __restrict__ dist) {
  const int l = threadIdx.x & 63;
  const int t = blockIdx.x * 4 + (threadIdx.x >> 6);
  const int w = blockIdx.y;
  const int b = blockIdx.z;
  const int row = w * 64 + l;
  const int col = t - l;
  float dd = 0.f;
  if ((unsigned)col < (unsigned)T_LEN) {
    const float4* o4 = (const float4*)(obs + ((size_t)b * T_LEN + row) * D_DIM);
    const float4* m4 = (const float4*)(mod + ((size_t)b * T_LEN + col) * D_DIM);
    float4 a0 = o4[0], a1 = o4[1], c0 = m4[0], c1 = m4[1];
    float acc = 0.f, df;
    df = a0.x - c0.x + EPSV; acc = fmaf(df, df, acc);
    df = a0.y - c0.y + EPSV; acc = fmaf(df, df, acc);
    df = a0.z - c0.z + EPSV; acc = fmaf(df, df, acc);
    df = a0.w - c0.w + EPSV; acc = fmaf(df, df, acc);
    df = a1.x - c1.x + EPSV; acc = fmaf(df, df, acc);
    df = a1.y - c1.y + EPSV; acc = fmaf(df, df, acc);
    df = a1.z - c1.z + EPSV; acc = fmaf(df, df, acc);
    df = a1.w - c1.w + EPSV; acc = fmaf(df, df, acc);
    dd = sqrtf(acc);
  }
  dist[(((size_t)b * NWAVE + w) * TSTEPS + t) * 64 + l] = (_Float16)dd;
}

// ---------------------------------------------------------------------------
// Strip-pipelined DTW. One block per batch. Wave w owns rows [64w, 64w+64).
// Lane l, local step t -> cell (row=64w+l, col=t-l). DPP wave_shr:1 carries
// the lane-to-lane dependency; an LDS ring carries the wave-to-wave boundary
// with a 2-super-step lag; __syncthreads() only once per 64 steps.
// ---------------------------------------------------------------------------
template<int PRE>
__global__ __launch_bounds__(1024)
void dtw_kernel(const float* __restrict__ obs, const float* __restrict__ mod,
                const _Float16* __restrict__ dist, float* __restrict__ bres) {
  __shared__ float ringbuf[NWAVE - 1][RB];
  __shared__ float modl[T_LEN * D_DIM];   // used by fused path only

  const int tid = threadIdx.x;
  const int b   = blockIdx.x;
  const int l   = tid & 63;
  const int w   = tid >> 6;

  float obsp[8];
  float mrow[8];
  if constexpr (!PRE) {
    // stage modeled[b] into LDS (2048 float4 / 1024 threads)
    const float4* msrc = (const float4*)(mod + (size_t)b * T_LEN * D_DIM);
    float4* mdst = (float4*)modl;
    mdst[tid]        = msrc[tid];
    mdst[tid + 1024] = msrc[tid + 1024];
    // own observed row (+eps) in registers
    const float* orow = obs + ((size_t)b * T_LEN + w * 64 + l) * D_DIM;
    float4 a0 = ((const float4*)orow)[0];
    float4 a1 = ((const float4*)orow)[1];
    obsp[0] = a0.x + EPSV; obsp[1] = a0.y + EPSV; obsp[2] = a0.z + EPSV; obsp[3] = a0.w + EPSV;
    obsp[4] = a1.x + EPSV; obsp[5] = a1.y + EPSV; obsp[6] = a1.z + EPSV; obsp[7] = a1.w + EPSV;
#pragma unroll
    for (int d = 0; d < 8; ++d) mrow[d] = 0.f;
  }
  __syncthreads();

  const _Float16* dptr = dist + ((size_t)b * NWAVE + w) * TSTEPS * 64 + l;  // PRE only

  float c = BIGV, p = BIGV, rprev = BIGV;
  const bool lane0  = (l == 0);
  const bool lane63 = (l == 63);
  const int  rdw    = (w > 0) ? (w - 1) : 0;
  const bool w0     = (w == 0);
  const bool wlast  = (w == NWAVE - 1);

  const int NSS = 2 * (NWAVE - 1) + TSTEPS / 64;   // 30 + 17 = 47 super-steps
  for (int ss = 0; ss < NSS; ++ss) {
    const int t0 = (ss - 2 * w) * 64;              // wave-uniform
    if (t0 >= 0 && t0 < TSTEPS) {
#pragma unroll 8
      for (int q = 0; q < 64; ++q) {
        const int t = t0 + q;
        float dd;
        if constexpr (PRE) {
          dd = (float)dptr[(size_t)t * 64];
        } else {
          // modeled row pipeline: shift down one lane, lane0 injects modeled[t]
#pragma unroll
          for (int d = 0; d < 8; ++d) mrow[d] = dpp_shr1(mrow[d]);
          if (lane0) {
            const int tm = (t < T_LEN) ? t : (T_LEN - 1);
            const float4* mr = (const float4*)(modl + tm * 8);
            float4 m0 = mr[0], m1 = mr[1];
            mrow[0] = m0.x; mrow[1] = m0.y; mrow[2] = m0.z; mrow[3] = m0.w;
            mrow[4] = m1.x; mrow[5] = m1.y; mrow[6] = m1.z; mrow[7] = m1.w;
          }
          float acc = 0.f;
#pragma unroll
          for (int d = 0; d < 8; ++d) { float df = obsp[d] - mrow[d]; acc = fmaf(df, df, acc); }
          dd = sqrtf(acc);
        }

        // cross-lane deps: c_up = dtw[i-1][j], p_up = dtw[i-1][j-1]
        float c_up = dpp_shr1(c);
        float p_up = dpp_shr1(p);
        float ringv = ringbuf[rdw][t & (RB - 1)];   // broadcast read (same addr all lanes)
        if (lane0) {
          c_up = w0 ? BIGV : ringv;
          p_up = w0 ? BIGV : rprev;
        }
        rprev = ringv;

        const int j = t - l;
        const bool valid = ((unsigned)j < (unsigned)T_LEN);
        float best = fminf(fminf(c_up, p_up), c);
        if (w0 && t == 0) { if (lane0) best = 0.f; }   // cell (0,0)
        float cur = valid ? (dd + best) : BIGV;
        p = c; c = cur;

        // publish bottom row of this strip for the next wave
        if (lane63 && !wlast && t >= 63 && t < 1087)
          ringbuf[w][(t - 63) & (RB - 1)] = c;
      }
    }
    __syncthreads();
  }

  // after padded final step t=1087 (invalid), p holds dtw[T-1][T-1]
  if (tid == 1023) bres[b] = p;
}

__global__ void mean_kernel(const float* __restrict__ bres, float* __restrict__ out, int B) {
  if (threadIdx.x == 0) {
    float s = 0.f;
    for (int i = 0; i < B; ++i) s += bres[i];
    out[0] = s / (float)B;
  }
}

extern "C" void kernel_launch(void* const* d_in, const int* in_sizes, int n_in,
                              void* d_out, int out_size, void* d_ws, size_t ws_size,
                              hipStream_t stream) {
  (void)n_in; (void)out_size;
  const float* obs = (const float*)d_in[0];
  const float* mod = (const float*)d_in[1];
  float* out = (float*)d_out;
  const int B = in_sizes[0] / (T_LEN * D_DIM);

  float* bres = (float*)d_ws;                               // B floats
  _Float16* dist = (_Float16*)((char*)d_ws + 256);          // dist scratch
  const size_t need = 256 + (size_t)B * NWAVE * TSTEPS * 64 * sizeof(_Float16);

  if (ws_size >= need) {
    dist_kernel<<<dim3(TSTEPS / 4, NWAVE, B), 256, 0, stream>>>(obs, mod, dist);
    dtw_kernel<1><<<B, 1024, 0, stream>>>(obs, mod, dist, bres);
  } else {
    dtw_kernel<0><<<B, 1024, 0, stream>>>(obs, mod, dist, bres);
  }
  mean_kernel<<<1, 64, 0, stream>>>(bres, out, B);
}

// Round 4
// 348.794 us; speedup vs baseline: 2.7069x; 2.7069x over previous
//
#include <hip/hip_runtime.h>

#define T_LEN  1024
#define D_DIM  8
#define NWAVE  16          // waves per DTW block = T/64
#define NTILE  17          // 64-step tiles per wave (1088 local steps)
#define TSTEPS 1088
#define RB     256         // ring entries (power of 2)
#define NSS    47          // 2*(NWAVE-1) + NTILE super-steps
#define BIGV   1e30f
#define EPSV   1e-6f

typedef _Float16 half2v __attribute__((ext_vector_type(2)));

__device__ __forceinline__ float dpp_shr1(float x) {   // dst[n] = src[n-1]
  int xi = __builtin_bit_cast(int, x);
  int r = __builtin_amdgcn_update_dpp(xi, xi, 0x138, 0xf, 0xf, false);
  return __builtin_bit_cast(float, r);
}

// ---------------------------------------------------------------------------
// dist2: dist[b][w][lt][l][q] (fp16), q = step-in-tile; 64 halfs (128B)
// contiguous per (lane l, tile lt) so the DTW kernel can load a whole tile
// with 8 dwordx4. Invalid cells (col out of range) stored as +inf (the DTW
// valid-mask overrides them anyway).
// ---------------------------------------------------------------------------
__global__ __launch_bounds__(256)
void dist2_kernel(const float* __restrict__ obs, const float* __restrict__ mod,
                  _Float16* __restrict__ dist) {
  const int q  = threadIdx.x & 63;
  const int wv = threadIdx.x >> 6;       // 0..3
  const int lt = blockIdx.x % NTILE;
  const int lg = blockIdx.x / NTILE;     // 0..15
  const int l  = lg * 4 + wv;
  const int w  = blockIdx.y;
  const int b  = blockIdx.z;
  const int t  = lt * 64 + q;
  const int col = t - l;
  const int row = w * 64 + l;
  float dd;
  if ((unsigned)col < (unsigned)T_LEN) {
    const float4* o4 = (const float4*)(obs + ((size_t)b * T_LEN + row) * D_DIM);
    const float4* m4 = (const float4*)(mod + ((size_t)b * T_LEN + col) * D_DIM);
    float4 a0 = o4[0], a1 = o4[1], c0 = m4[0], c1 = m4[1];
    float acc = 0.f, df;
    df = a0.x - c0.x + EPSV; acc = fmaf(df, df, acc);
    df = a0.y - c0.y + EPSV; acc = fmaf(df, df, acc);
    df = a0.z - c0.z + EPSV; acc = fmaf(df, df, acc);
    df = a0.w - c0.w + EPSV; acc = fmaf(df, df, acc);
    df = a1.x - c1.x + EPSV; acc = fmaf(df, df, acc);
    df = a1.y - c1.y + EPSV; acc = fmaf(df, df, acc);
    df = a1.z - c1.z + EPSV; acc = fmaf(df, df, acc);
    df = a1.w - c1.w + EPSV; acc = fmaf(df, df, acc);
    dd = sqrtf(acc);
  } else {
    dd = __builtin_inff();
  }
  dist[(((size_t)(b * NWAVE + w) * NTILE + lt) * 64 + l) * 64 + q] = (_Float16)dd;
}

// ---------------------------------------------------------------------------
// dtw3: R2's VERIFIED inner loop (per-step LDS ring broadcast read, per-step
// lane63 ring write, rprev chain, valid-mask) with exactly one change:
// dd comes from a register double-buffer (8x dwordx4 per superstep, tile
// lt+1 prefetched while computing tile lt).
// ---------------------------------------------------------------------------
__global__ __launch_bounds__(1024)
void dtw3_kernel(const _Float16* __restrict__ dist, float* __restrict__ bres) {
  __shared__ float ringbuf[NWAVE - 1][RB];

  const int tid = threadIdx.x;
  const int b   = blockIdx.x;
  const int l   = tid & 63;
  const int w   = tid >> 6;
  const bool lane0  = (l == 0);
  const bool lane63 = (l == 63);
  const int  rdw    = (w > 0) ? (w - 1) : 0;
  const bool w0     = (w == 0);
  const bool wlast  = (w == NWAVE - 1);

  const _Float16* base = dist + (size_t)(b * NWAVE + w) * NTILE * 4096 + l * 64;

  unsigned bufA[32], bufB[32];
  // preload this wave's tile 0 into A
#pragma unroll
  for (int k = 0; k < 8; ++k) {
    uint4 v = ((const uint4*)base)[k];
    bufA[4 * k + 0] = v.x; bufA[4 * k + 1] = v.y;
    bufA[4 * k + 2] = v.z; bufA[4 * k + 3] = v.w;
  }

  float c = BIGV, p = BIGV, rprev = BIGV;

  auto step_tile = [&](unsigned (&cur)[32], unsigned (&nxt)[32], int ss) {
    const int t0 = (ss - 2 * w) * 64;              // wave-uniform
    if (t0 < 0 || t0 >= TSTEPS) return;
    const int lt = t0 >> 6;
    if (lt < NTILE - 1) {                          // prefetch next tile
      const uint4* np = (const uint4*)(base + (size_t)(lt + 1) * 4096);
#pragma unroll
      for (int k = 0; k < 8; ++k) {
        uint4 v = np[k];
        nxt[4 * k + 0] = v.x; nxt[4 * k + 1] = v.y;
        nxt[4 * k + 2] = v.z; nxt[4 * k + 3] = v.w;
      }
    }
#pragma unroll
    for (int q = 0; q < 64; ++q) {
      const int t = t0 + q;
      half2v hh = __builtin_bit_cast(half2v, cur[q >> 1]);
      float dd = (float)hh[q & 1];

      float c_up = dpp_shr1(c);
      float p_up = dpp_shr1(p);
      float ringv = ringbuf[rdw][t & (RB - 1)];    // broadcast read
      if (lane0) { c_up = w0 ? BIGV : ringv; p_up = w0 ? BIGV : rprev; }
      rprev = ringv;

      const int j = t - l;
      const bool valid = ((unsigned)j < (unsigned)T_LEN);
      float best = fminf(fminf(c_up, p_up), c);
      if (w0 && t == 0) { if (lane0) best = 0.f; } // cell (0,0)
      float cur_v = valid ? (dd + best) : BIGV;
      p = c; c = cur_v;

      if (lane63 && !wlast && t >= 63 && t < TSTEPS - 1)
        ringbuf[w][(t - 63) & (RB - 1)] = c;       // per-step boundary publish
    }
  };

  for (int ss = 0; ss < NSS; ss += 2) {
    step_tile(bufA, bufB, ss);
    __syncthreads();
    step_tile(bufB, bufA, ss + 1);
    __syncthreads();
  }

  // after padded final step (t=1087, invalid), p holds dtw[T-1][T-1]
  if (tid == 1023) bres[b] = p;
}

// ---------------------------------------------------------------------------
// Fallback (no workspace): fused distance, per-step LDS ring.
// ---------------------------------------------------------------------------
__global__ __launch_bounds__(1024)
void dtw_fused_kernel(const float* __restrict__ obs, const float* __restrict__ mod,
                      float* __restrict__ bres) {
  __shared__ float ringbuf[NWAVE - 1][RB];
  __shared__ float modl[T_LEN * D_DIM];

  const int tid = threadIdx.x;
  const int b   = blockIdx.x;
  const int l   = tid & 63;
  const int w   = tid >> 6;

  const float4* msrc = (const float4*)(mod + (size_t)b * T_LEN * D_DIM);
  float4* mdst = (float4*)modl;
  mdst[tid]        = msrc[tid];
  mdst[tid + 1024] = msrc[tid + 1024];
  const float* orow = obs + ((size_t)b * T_LEN + w * 64 + l) * D_DIM;
  float4 a0 = ((const float4*)orow)[0];
  float4 a1 = ((const float4*)orow)[1];
  float obsp[8] = {a0.x + EPSV, a0.y + EPSV, a0.z + EPSV, a0.w + EPSV,
                   a1.x + EPSV, a1.y + EPSV, a1.z + EPSV, a1.w + EPSV};
  float mrow[8] = {0.f, 0.f, 0.f, 0.f, 0.f, 0.f, 0.f, 0.f};
  __syncthreads();

  float c = BIGV, p = BIGV, rprev = BIGV;
  const bool lane0  = (l == 0);
  const bool lane63 = (l == 63);
  const int  rdw    = (w > 0) ? (w - 1) : 0;
  const bool w0     = (w == 0);
  const bool wlast  = (w == NWAVE - 1);

  for (int ss = 0; ss < NSS; ++ss) {
    const int t0 = (ss - 2 * w) * 64;
    if (t0 >= 0 && t0 < TSTEPS) {
#pragma unroll 8
      for (int q = 0; q < 64; ++q) {
        const int t = t0 + q;
#pragma unroll
        for (int d = 0; d < 8; ++d) mrow[d] = dpp_shr1(mrow[d]);
        if (lane0) {
          const int tm = (t < T_LEN) ? t : (T_LEN - 1);
          const float4* mr = (const float4*)(modl + tm * 8);
          float4 m0 = mr[0], m1 = mr[1];
          mrow[0] = m0.x; mrow[1] = m0.y; mrow[2] = m0.z; mrow[3] = m0.w;
          mrow[4] = m1.x; mrow[5] = m1.y; mrow[6] = m1.z; mrow[7] = m1.w;
        }
        float acc = 0.f;
#pragma unroll
        for (int d = 0; d < 8; ++d) { float df = obsp[d] - mrow[d]; acc = fmaf(df, df, acc); }
        float dd = sqrtf(acc);

        float c_up = dpp_shr1(c);
        float p_up = dpp_shr1(p);
        float ringv = ringbuf[rdw][t & (RB - 1)];
        if (lane0) { c_up = w0 ? BIGV : ringv; p_up = w0 ? BIGV : rprev; }
        rprev = ringv;

        const int j = t - l;
        const bool valid = ((unsigned)j < (unsigned)T_LEN);
        float best = fminf(fminf(c_up, p_up), c);
        if (w0 && t == 0) { if (lane0) best = 0.f; }
        float cur = valid ? (dd + best) : BIGV;
        p = c; c = cur;

        if (lane63 && !wlast && t >= 63 && t < TSTEPS - 1)
          ringbuf[w][(t - 63) & (RB - 1)] = c;
      }
    }
    __syncthreads();
  }
  if (tid == 1023) bres[b] = p;
}

__global__ void mean_kernel(const float* __restrict__ bres, float* __restrict__ out, int B) {
  if (threadIdx.x == 0) {
    float s = 0.f;
    for (int i = 0; i < B; ++i) s += bres[i];
    out[0] = s / (float)B;
  }
}

extern "C" void kernel_launch(void* const* d_in, const int* in_sizes, int n_in,
                              void* d_out, int out_size, void* d_ws, size_t ws_size,
                              hipStream_t stream) {
  (void)n_in; (void)out_size;
  const float* obs = (const float*)d_in[0];
  const float* mod = (const float*)d_in[1];
  float* out = (float*)d_out;
  const int B = in_sizes[0] / (T_LEN * D_DIM);

  float* bres = (float*)d_ws;                            // B floats
  _Float16* dist = (_Float16*)((char*)d_ws + 256);       // dist scratch
  const size_t need = 256 + (size_t)B * NWAVE * NTILE * 64 * 64 * sizeof(_Float16);

  if (ws_size >= need) {
    dist2_kernel<<<dim3(NTILE * 16, NWAVE, B), 256, 0, stream>>>(obs, mod, dist);
    dtw3_kernel<<<B, 1024, 0, stream>>>(dist, bres);
  } else {
    dtw_fused_kernel<<<B, 1024, 0, stream>>>(obs, mod, bres);
  }
  mean_kernel<<<1, 64, 0, stream>>>(bres, out, B);
}

// Round 5
// 266.517 us; speedup vs baseline: 3.5426x; 1.3087x over previous
//
#include <hip/hip_runtime.h>

#define T_LEN  1024
#define D_DIM  8
#define NWAVE  16          // waves per DTW block = T/64
#define NTILE  17          // 64-step tiles per wave (1088 local steps)
#define TSTEPS 1088
#define RB     256         // ring entries (power of 2)
#define NSS    47          // 2*(NWAVE-1) + NTILE super-steps
#define BIGV   1e30f
#define EPSV   1e-6f

typedef _Float16 half2v __attribute__((ext_vector_type(2)));

__device__ __forceinline__ float dpp_shr1(float x) {   // dst[n] = src[n-1]; lane0 keeps old
  int xi = __builtin_bit_cast(int, x);
  int r = __builtin_amdgcn_update_dpp(xi, xi, 0x138, 0xf, 0xf, false);
  return __builtin_bit_cast(float, r);
}
__device__ __forceinline__ float dpp_shl1(float x) {   // dst[n] = src[n+1]; lane63 keeps old
  int xi = __builtin_bit_cast(int, x);
  int r = __builtin_amdgcn_update_dpp(xi, xi, 0x130, 0xf, 0xf, false);
  return __builtin_bit_cast(float, r);
}

// ---------------------------------------------------------------------------
// dist2: dist[b][w][lt][l][q] (fp16), q = step-in-tile; 64 halfs (128B)
// contiguous per (lane l, tile lt). Invalid cells (col out of range) = +inf.
// ---------------------------------------------------------------------------
__global__ __launch_bounds__(256)
void dist2_kernel(const float* __restrict__ obs, const float* __restrict__ mod,
                  _Float16* __restrict__ dist) {
  const int q  = threadIdx.x & 63;
  const int wv = threadIdx.x >> 6;       // 0..3
  const int lt = blockIdx.x % NTILE;
  const int lg = blockIdx.x / NTILE;     // 0..15
  const int l  = lg * 4 + wv;
  const int w  = blockIdx.y;
  const int b  = blockIdx.z;
  const int t  = lt * 64 + q;
  const int col = t - l;
  const int row = w * 64 + l;
  float dd;
  if ((unsigned)col < (unsigned)T_LEN) {
    const float4* o4 = (const float4*)(obs + ((size_t)b * T_LEN + row) * D_DIM);
    const float4* m4 = (const float4*)(mod + ((size_t)b * T_LEN + col) * D_DIM);
    float4 a0 = o4[0], a1 = o4[1], c0 = m4[0], c1 = m4[1];
    float acc = 0.f, df;
    df = a0.x - c0.x + EPSV; acc = fmaf(df, df, acc);
    df = a0.y - c0.y + EPSV; acc = fmaf(df, df, acc);
    df = a0.z - c0.z + EPSV; acc = fmaf(df, df, acc);
    df = a0.w - c0.w + EPSV; acc = fmaf(df, df, acc);
    df = a1.x - c1.x + EPSV; acc = fmaf(df, df, acc);
    df = a1.y - c1.y + EPSV; acc = fmaf(df, df, acc);
    df = a1.z - c1.z + EPSV; acc = fmaf(df, df, acc);
    df = a1.w - c1.w + EPSV; acc = fmaf(df, df, acc);
    dd = sqrtf(acc);
  } else {
    dd = __builtin_inff();
  }
  dist[(((size_t)(b * NWAVE + w) * NTILE + lt) * 64 + l) * 64 + q] = (_Float16)dd;
}

// ---------------------------------------------------------------------------
// dtw4: R4 (verified) with ONE change — the per-step ring ds_read is replaced
// by a batched coalesced read at tile start, rotated lane-wise per step via
// dpp wave_shl:1.  Per-step lane63 ds_write kept exactly as R4 (guarded to
// entries [0,1023]; slot-disjointness vs all same-superstep reads verified
// mod 256).  Ring LDS initialized to BIGV; entry t0-1 at lt==0 explicitly
// BIGV (this was R3's uninitialized-read bug).
// ---------------------------------------------------------------------------
__global__ __launch_bounds__(1024)
void dtw4_kernel(const _Float16* __restrict__ dist, float* __restrict__ bres) {
  __shared__ float ringbuf[NWAVE - 1][RB];

  const int tid = threadIdx.x;
  const int b   = blockIdx.x;
  const int l   = tid & 63;
  const int w   = tid >> 6;
  const bool lane0  = (l == 0);
  const bool lane63 = (l == 63);
  const bool w0     = (w == 0);
  const bool wlast  = (w == NWAVE - 1);

  // init ring to BIGV (R2/R4 semantic default for never-written entries)
  {
    float* rp = &ringbuf[0][0];
    for (int k = tid; k < (NWAVE - 1) * RB; k += 1024) rp[k] = BIGV;
  }

  const _Float16* base = dist + (size_t)(b * NWAVE + w) * NTILE * 4096 + l * 64;

  unsigned bufA[32], bufB[32];
#pragma unroll
  for (int k = 0; k < 8; ++k) {
    uint4 v = ((const uint4*)base)[k];
    bufA[4 * k + 0] = v.x; bufA[4 * k + 1] = v.y;
    bufA[4 * k + 2] = v.z; bufA[4 * k + 3] = v.w;
  }
  __syncthreads();   // covers both ring-init and (harmlessly) the preload

  float c = BIGV, p = BIGV;

  auto step_tile = [&](unsigned (&cur)[32], unsigned (&nxt)[32], int ss) {
    const int t0 = (ss - 2 * w) * 64;              // wave-uniform
    if (t0 < 0 || t0 >= TSTEPS) return;
    const int lt = t0 >> 6;
    if (lt < NTILE - 1) {                          // prefetch next dist tile
      const uint4* np = (const uint4*)(base + (size_t)(lt + 1) * 4096);
#pragma unroll
      for (int k = 0; k < 8; ++k) {
        uint4 v = np[k];
        nxt[4 * k + 0] = v.x; nxt[4 * k + 1] = v.y;
        nxt[4 * k + 2] = v.z; nxt[4 * k + 3] = v.w;
      }
    }
    // batched ring read: lane l <- entry t0+l; rvo <- entry t0-1 (broadcast)
    float rv, rvo;
    if (w0) {
      rv = BIGV; rvo = BIGV;
    } else {
      rv  = ringbuf[w - 1][(t0 + l) & (RB - 1)];
      rvo = (lt == 0) ? BIGV : ringbuf[w - 1][(t0 - 1) & (RB - 1)];
    }
#pragma unroll
    for (int q = 0; q < 64; ++q) {
      const int t = t0 + q;
      half2v hh = __builtin_bit_cast(half2v, cur[q >> 1]);
      float dd = (float)hh[q & 1];

      float cu = dpp_shr1(c);                      // dtw[i-1][j]
      float pu = dpp_shr1(p);                      // dtw[i-1][j-1]
      cu = lane0 ? rv  : cu;                       // lane0: from ring (rotated)
      pu = lane0 ? rvo : pu;

      float best = fminf(fminf(cu, pu), c);
      if (q == 0 && lt == 0) { if (w0 && lane0) best = 0.f; }  // cell (0,0)
      float cv = dd + best;                        // dd=+inf marks invalid cells
      p = c; c = cv;

      rvo = rv;                                    // lane0: entry t0+q for next pu
      rv = dpp_shl1(rv);                           // lane0 <- entry t0+q+1

      if (lane63 && !wlast && t >= 63 && t < TSTEPS - 1)
        ringbuf[w][(t - 63) & (RB - 1)] = c;       // per-step publish (R4-verified)
    }
  };

  for (int ss = 0; ss < NSS; ss += 2) {
    step_tile(bufA, bufB, ss);
    __syncthreads();
    step_tile(bufB, bufA, ss + 1);
    __syncthreads();
  }

  // after padded final step (t=1087, dd=inf), p holds dtw[T-1][T-1]
  if (tid == 1023) bres[b] = p;
}

// ---------------------------------------------------------------------------
// Fallback (no workspace): fused distance, per-step LDS ring (R2-verified).
// ---------------------------------------------------------------------------
__global__ __launch_bounds__(1024)
void dtw_fused_kernel(const float* __restrict__ obs, const float* __restrict__ mod,
                      float* __restrict__ bres) {
  __shared__ float ringbuf[NWAVE - 1][RB];
  __shared__ float modl[T_LEN * D_DIM];

  const int tid = threadIdx.x;
  const int b   = blockIdx.x;
  const int l   = tid & 63;
  const int w   = tid >> 6;

  const float4* msrc = (const float4*)(mod + (size_t)b * T_LEN * D_DIM);
  float4* mdst = (float4*)modl;
  mdst[tid]        = msrc[tid];
  mdst[tid + 1024] = msrc[tid + 1024];
  const float* orow = obs + ((size_t)b * T_LEN + w * 64 + l) * D_DIM;
  float4 a0 = ((const float4*)orow)[0];
  float4 a1 = ((const float4*)orow)[1];
  float obsp[8] = {a0.x + EPSV, a0.y + EPSV, a0.z + EPSV, a0.w + EPSV,
                   a1.x + EPSV, a1.y + EPSV, a1.z + EPSV, a1.w + EPSV};
  float mrow[8] = {0.f, 0.f, 0.f, 0.f, 0.f, 0.f, 0.f, 0.f};
  __syncthreads();

  float c = BIGV, p = BIGV, rprev = BIGV;
  const bool lane0  = (l == 0);
  const bool lane63 = (l == 63);
  const int  rdw    = (w > 0) ? (w - 1) : 0;
  const bool w0     = (w == 0);
  const bool wlast  = (w == NWAVE - 1);

  for (int ss = 0; ss < NSS; ++ss) {
    const int t0 = (ss - 2 * w) * 64;
    if (t0 >= 0 && t0 < TSTEPS) {
#pragma unroll 8
      for (int q = 0; q < 64; ++q) {
        const int t = t0 + q;
#pragma unroll
        for (int d = 0; d < 8; ++d) mrow[d] = dpp_shr1(mrow[d]);
        if (lane0) {
          const int tm = (t < T_LEN) ? t : (T_LEN - 1);
          const float4* mr = (const float4*)(modl + tm * 8);
          float4 m0 = mr[0], m1 = mr[1];
          mrow[0] = m0.x; mrow[1] = m0.y; mrow[2] = m0.z; mrow[3] = m0.w;
          mrow[4] = m1.x; mrow[5] = m1.y; mrow[6] = m1.z; mrow[7] = m1.w;
        }
        float acc = 0.f;
#pragma unroll
        for (int d = 0; d < 8; ++d) { float df = obsp[d] - mrow[d]; acc = fmaf(df, df, acc); }
        float dd = sqrtf(acc);

        float c_up = dpp_shr1(c);
        float p_up = dpp_shr1(p);
        float ringv = ringbuf[rdw][t & (RB - 1)];
        if (lane0) { c_up = w0 ? BIGV : ringv; p_up = w0 ? BIGV : rprev; }
        rprev = ringv;

        const int j = t - l;
        const bool valid = ((unsigned)j < (unsigned)T_LEN);
        float best = fminf(fminf(c_up, p_up), c);
        if (w0 && t == 0) { if (lane0) best = 0.f; }
        float cur = valid ? (dd + best) : BIGV;
        p = c; c = cur;

        if (lane63 && !wlast && t >= 63 && t < TSTEPS - 1)
          ringbuf[w][(t - 63) & (RB - 1)] = c;
      }
    }
    __syncthreads();
  }
  if (tid == 1023) bres[b] = p;
}

__global__ void mean_kernel(const float* __restrict__ bres, float* __restrict__ out, int B) {
  if (threadIdx.x == 0) {
    float s = 0.f;
    for (int i = 0; i < B; ++i) s += bres[i];
    out[0] = s / (float)B;
  }
}

extern "C" void kernel_launch(void* const* d_in, const int* in_sizes, int n_in,
                              void* d_out, int out_size, void* d_ws, size_t ws_size,
                              hipStream_t stream) {
  (void)n_in; (void)out_size;
  const float* obs = (const float*)d_in[0];
  const float* mod = (const float*)d_in[1];
  float* out = (float*)d_out;
  const int B = in_sizes[0] / (T_LEN * D_DIM);

  float* bres = (float*)d_ws;                            // B floats
  _Float16* dist = (_Float16*)((char*)d_ws + 256);       // dist scratch
  const size_t need = 256 + (size_t)B * NWAVE * NTILE * 64 * 64 * sizeof(_Float16);

  if (ws_size >= need) {
    dist2_kernel<<<dim3(NTILE * 16, NWAVE, B), 256, 0, stream>>>(obs, mod, dist);
    dtw4_kernel<<<B, 1024, 0, stream>>>(dist, bres);
  } else {
    dtw_fused_kernel<<<B, 1024, 0, stream>>>(obs, mod, bres);
  }
  mean_kernel<<<1, 64, 0, stream>>>(bres, out, B);
}

// Round 6
// 242.696 us; speedup vs baseline: 3.8903x; 1.0982x over previous
//
#include <hip/hip_runtime.h>

#define T_LEN  1024
#define D_DIM  8
#define NWAVE  16          // waves per DTW block = T/64
#define NTILE  17          // 64-step tiles per wave (1088 local steps)
#define TSTEPS 1088
#define RB     256         // ring entries (power of 2)
#define NSS    47          // 2*(NWAVE-1) + NTILE super-steps
#define BIGV   1e30f
#define EPSV   1e-6f

typedef _Float16 half2v __attribute__((ext_vector_type(2)));

__device__ __forceinline__ float dpp_shr1(float x) {   // dst[n] = src[n-1]; lane0 keeps old
  int xi = __builtin_bit_cast(int, x);
  int r = __builtin_amdgcn_update_dpp(xi, xi, 0x138, 0xf, 0xf, false);
  return __builtin_bit_cast(float, r);
}
__device__ __forceinline__ float dpp_shl1(float x) {   // dst[n] = src[n+1]; lane63 keeps old
  int xi = __builtin_bit_cast(int, x);
  int r = __builtin_amdgcn_update_dpp(xi, xi, 0x130, 0xf, 0xf, false);
  return __builtin_bit_cast(float, r);
}

// ---------------------------------------------------------------------------
// dist2: dist[b][w][lt][l][q] (fp16), q = step-in-tile; 64 halfs (128B)
// contiguous per (lane l, tile lt). Invalid cells (col out of range) = +inf.
// ---------------------------------------------------------------------------
__global__ __launch_bounds__(256)
void dist2_kernel(const float* __restrict__ obs, const float* __restrict__ mod,
                  _Float16* __restrict__ dist) {
  const int q  = threadIdx.x & 63;
  const int wv = threadIdx.x >> 6;       // 0..3
  const int lt = blockIdx.x % NTILE;
  const int lg = blockIdx.x / NTILE;     // 0..15
  const int l  = lg * 4 + wv;
  const int w  = blockIdx.y;
  const int b  = blockIdx.z;
  const int t  = lt * 64 + q;
  const int col = t - l;
  const int row = w * 64 + l;
  float dd;
  if ((unsigned)col < (unsigned)T_LEN) {
    const float4* o4 = (const float4*)(obs + ((size_t)b * T_LEN + row) * D_DIM);
    const float4* m4 = (const float4*)(mod + ((size_t)b * T_LEN + col) * D_DIM);
    float4 a0 = o4[0], a1 = o4[1], c0 = m4[0], c1 = m4[1];
    float acc = 0.f, df;
    df = a0.x - c0.x + EPSV; acc = fmaf(df, df, acc);
    df = a0.y - c0.y + EPSV; acc = fmaf(df, df, acc);
    df = a0.z - c0.z + EPSV; acc = fmaf(df, df, acc);
    df = a0.w - c0.w + EPSV; acc = fmaf(df, df, acc);
    df = a1.x - c1.x + EPSV; acc = fmaf(df, df, acc);
    df = a1.y - c1.y + EPSV; acc = fmaf(df, df, acc);
    df = a1.z - c1.z + EPSV; acc = fmaf(df, df, acc);
    df = a1.w - c1.w + EPSV; acc = fmaf(df, df, acc);
    dd = sqrtf(acc);
  } else {
    dd = __builtin_inff();
  }
  dist[(((size_t)(b * NWAVE + w) * NTILE + lt) * 64 + l) * 64 + q] = (_Float16)dd;
}

// ---------------------------------------------------------------------------
// dtw5: R5's VERIFIED dataflow with the double buffer forced into registers:
// 16 named uint4 (a0..a7 / b0..b7), static accesses only, no arrays/lambdas.
// ---------------------------------------------------------------------------

// one DTW step; DD = dist value (float), Q = static step-in-tile, FIX0 = (Q==0)
#define DTW_STEP(DD, Q, FIX0)                                              \
  {                                                                        \
    const float dd_ = (DD);                                                \
    float cu = dpp_shr1(c);                                                \
    float pu = dpp_shr1(p);                                                \
    cu = lane0 ? rv  : cu;                                                 \
    pu = lane0 ? rvo : pu;                                                 \
    float best = fminf(fminf(cu, pu), c);                                  \
    if (FIX0 && LT == 0) { if (w0 && lane0) best = 0.f; }                  \
    float cv = dd_ + best;                                                 \
    p = c; c = cv;                                                         \
    rvo = rv; rv = dpp_shl1(rv);                                           \
    const int t_ = T0 + (Q);                                               \
    if (lane63 && !wlast && t_ >= 63 && t_ < TSTEPS - 1)                   \
      ringbuf[w][(t_ - 63) & (RB - 1)] = c;                                \
  }

#define DTW_STEP2(U, QB)                                                   \
  {                                                                        \
    half2v hh_ = __builtin_bit_cast(half2v, (unsigned)(U));                \
    DTW_STEP((float)hh_[0], (QB), ((QB) == 0))                             \
    DTW_STEP((float)hh_[1], (QB) + 1, 0)                                   \
  }

#define DTW_STEP8(V, QB)                                                   \
  DTW_STEP2((V).x, (QB))                                                   \
  DTW_STEP2((V).y, (QB) + 2)                                               \
  DTW_STEP2((V).z, (QB) + 4)                                               \
  DTW_STEP2((V).w, (QB) + 6)

// one superstep: consume C0..C7 (current tile), prefetch N0..N7 (next tile)
#define DTW_TILE(SS, C0, C1, C2, C3, C4, C5, C6, C7,                       \
                     N0, N1, N2, N3, N4, N5, N6, N7)                       \
  {                                                                        \
    const int T0 = ((SS) - 2 * w) * 64;                                    \
    if (T0 >= 0 && T0 < TSTEPS) {                                          \
      const int LT = T0 >> 6;                                              \
      if (LT < NTILE - 1) {                                                \
        const uint4* np_ = (const uint4*)(base + (size_t)(LT + 1) * 4096); \
        N0 = np_[0]; N1 = np_[1]; N2 = np_[2]; N3 = np_[3];                \
        N4 = np_[4]; N5 = np_[5]; N6 = np_[6]; N7 = np_[7];                \
      }                                                                    \
      float rv, rvo;                                                       \
      if (w0) { rv = BIGV; rvo = BIGV; }                                   \
      else {                                                               \
        rv  = ringbuf[w - 1][(T0 + l) & (RB - 1)];                         \
        rvo = (LT == 0) ? BIGV : ringbuf[w - 1][(T0 - 1) & (RB - 1)];      \
      }                                                                    \
      DTW_STEP8(C0, 0)  DTW_STEP8(C1, 8)  DTW_STEP8(C2, 16)                \
      DTW_STEP8(C3, 24) DTW_STEP8(C4, 32) DTW_STEP8(C5, 40)                \
      DTW_STEP8(C6, 48) DTW_STEP8(C7, 56)                                  \
    }                                                                      \
  }

__global__ __launch_bounds__(1024)
void dtw5_kernel(const _Float16* __restrict__ dist, float* __restrict__ bres) {
  __shared__ float ringbuf[NWAVE - 1][RB];

  const int tid = threadIdx.x;
  const int b   = blockIdx.x;
  const int l   = tid & 63;
  const int w   = tid >> 6;
  const bool lane0  = (l == 0);
  const bool lane63 = (l == 63);
  const bool w0     = (w == 0);
  const bool wlast  = (w == NWAVE - 1);

  // init ring to BIGV (default for never-written entries)
  {
    float* rp = &ringbuf[0][0];
    for (int k = tid; k < (NWAVE - 1) * RB; k += 1024) rp[k] = BIGV;
  }

  const _Float16* base = dist + (size_t)(b * NWAVE + w) * NTILE * 4096 + l * 64;

  uint4 a0, a1, a2, a3, a4, a5, a6, a7;
  uint4 b0, b1, b2, b3, b4, b5, b6, b7;
  {
    const uint4* tp = (const uint4*)base;   // this wave's tile 0
    a0 = tp[0]; a1 = tp[1]; a2 = tp[2]; a3 = tp[3];
    a4 = tp[4]; a5 = tp[5]; a6 = tp[6]; a7 = tp[7];
  }
  // silence "maybe-uninitialized" paths cheaply (b* assigned before any use)
  b0 = a0; b1 = a1; b2 = a2; b3 = a3; b4 = a4; b5 = a5; b6 = a6; b7 = a7;

  __syncthreads();   // covers ring-init

  float c = BIGV, p = BIGV;

  for (int ss = 0; ss < NSS; ss += 2) {
    DTW_TILE(ss,     a0, a1, a2, a3, a4, a5, a6, a7,
                     b0, b1, b2, b3, b4, b5, b6, b7)
    __syncthreads();
    DTW_TILE(ss + 1, b0, b1, b2, b3, b4, b5, b6, b7,
                     a0, a1, a2, a3, a4, a5, a6, a7)
    __syncthreads();
  }

  // after padded final step (t=1087, dd=inf), p holds dtw[T-1][T-1]
  if (tid == 1023) bres[b] = p;
}

// ---------------------------------------------------------------------------
// Fallback (no workspace): fused distance, per-step LDS ring (R2-verified).
// ---------------------------------------------------------------------------
__global__ __launch_bounds__(1024)
void dtw_fused_kernel(const float* __restrict__ obs, const float* __restrict__ mod,
                      float* __restrict__ bres) {
  __shared__ float ringbuf[NWAVE - 1][RB];
  __shared__ float modl[T_LEN * D_DIM];

  const int tid = threadIdx.x;
  const int b   = blockIdx.x;
  const int l   = tid & 63;
  const int w   = tid >> 6;

  const float4* msrc = (const float4*)(mod + (size_t)b * T_LEN * D_DIM);
  float4* mdst = (float4*)modl;
  mdst[tid]        = msrc[tid];
  mdst[tid + 1024] = msrc[tid + 1024];
  const float* orow = obs + ((size_t)b * T_LEN + w * 64 + l) * D_DIM;
  float4 a0 = ((const float4*)orow)[0];
  float4 a1 = ((const float4*)orow)[1];
  float obsp[8] = {a0.x + EPSV, a0.y + EPSV, a0.z + EPSV, a0.w + EPSV,
                   a1.x + EPSV, a1.y + EPSV, a1.z + EPSV, a1.w + EPSV};
  float mrow[8] = {0.f, 0.f, 0.f, 0.f, 0.f, 0.f, 0.f, 0.f};
  __syncthreads();

  float c = BIGV, p = BIGV, rprev = BIGV;
  const bool lane0  = (l == 0);
  const bool lane63 = (l == 63);
  const int  rdw    = (w > 0) ? (w - 1) : 0;
  const bool w0     = (w == 0);
  const bool wlast  = (w == NWAVE - 1);

  for (int ss = 0; ss < NSS; ++ss) {
    const int t0 = (ss - 2 * w) * 64;
    if (t0 >= 0 && t0 < TSTEPS) {
#pragma unroll 8
      for (int q = 0; q < 64; ++q) {
        const int t = t0 + q;
#pragma unroll
        for (int d = 0; d < 8; ++d) mrow[d] = dpp_shr1(mrow[d]);
        if (lane0) {
          const int tm = (t < T_LEN) ? t : (T_LEN - 1);
          const float4* mr = (const float4*)(modl + tm * 8);
          float4 m0 = mr[0], m1 = mr[1];
          mrow[0] = m0.x; mrow[1] = m0.y; mrow[2] = m0.z; mrow[3] = m0.w;
          mrow[4] = m1.x; mrow[5] = m1.y; mrow[6] = m1.z; mrow[7] = m1.w;
        }
        float acc = 0.f;
#pragma unroll
        for (int d = 0; d < 8; ++d) { float df = obsp[d] - mrow[d]; acc = fmaf(df, df, acc); }
        float dd = sqrtf(acc);

        float c_up = dpp_shr1(c);
        float p_up = dpp_shr1(p);
        float ringv = ringbuf[rdw][t & (RB - 1)];
        if (lane0) { c_up = w0 ? BIGV : ringv; p_up = w0 ? BIGV : rprev; }
        rprev = ringv;

        const int j = t - l;
        const bool valid = ((unsigned)j < (unsigned)T_LEN);
        float best = fminf(fminf(c_up, p_up), c);
        if (w0 && t == 0) { if (lane0) best = 0.f; }
        float cur = valid ? (dd + best) : BIGV;
        p = c; c = cur;

        if (lane63 && !wlast && t >= 63 && t < TSTEPS - 1)
          ringbuf[w][(t - 63) & (RB - 1)] = c;
      }
    }
    __syncthreads();
  }
  if (tid == 1023) bres[b] = p;
}

__global__ void mean_kernel(const float* __restrict__ bres, float* __restrict__ out, int B) {
  if (threadIdx.x == 0) {
    float s = 0.f;
    for (int i = 0; i < B; ++i) s += bres[i];
    out[0] = s / (float)B;
  }
}

extern "C" void kernel_launch(void* const* d_in, const int* in_sizes, int n_in,
                              void* d_out, int out_size, void* d_ws, size_t ws_size,
                              hipStream_t stream) {
  (void)n_in; (void)out_size;
  const float* obs = (const float*)d_in[0];
  const float* mod = (const float*)d_in[1];
  float* out = (float*)d_out;
  const int B = in_sizes[0] / (T_LEN * D_DIM);

  float* bres = (float*)d_ws;                            // B floats
  _Float16* dist = (_Float16*)((char*)d_ws + 256);       // dist scratch
  const size_t need = 256 + (size_t)B * NWAVE * NTILE * 64 * 64 * sizeof(_Float16);

  if (ws_size >= need) {
    dist2_kernel<<<dim3(NTILE * 16, NWAVE, B), 256, 0, stream>>>(obs, mod, dist);
    dtw5_kernel<<<B, 1024, 0, stream>>>(dist, bres);
  } else {
    dtw_fused_kernel<<<B, 1024, 0, stream>>>(obs, mod, bres);
  }
  mean_kernel<<<1, 64, 0, stream>>>(bres, out, B);
}

// Round 7
// 223.163 us; speedup vs baseline: 4.2308x; 1.0875x over previous
//
#include <hip/hip_runtime.h>

#define T_LEN  1024
#define D_DIM  8
#define NWAVE  16          // waves per DTW block = T/64
#define NTILE  17          // 64-step tiles per wave (1088 local steps)
#define TSTEPS 1088
#define RB     256         // ring entries (power of 2)
#define NSS    47          // 2*(NWAVE-1) + NTILE super-steps
#define BIGV   1e30f
#define EPSV   1e-6f

typedef _Float16 half2v __attribute__((ext_vector_type(2)));
typedef unsigned u32x4  __attribute__((ext_vector_type(4)));

__device__ __forceinline__ float dpp_shr1(float x) {   // dst[n] = src[n-1]; lane0 keeps old
  int xi = __builtin_bit_cast(int, x);
  int r = __builtin_amdgcn_update_dpp(xi, xi, 0x138, 0xf, 0xf, false);
  return __builtin_bit_cast(float, r);
}
__device__ __forceinline__ float dpp_shl1(float x) {   // dst[n] = src[n+1]; lane63 keeps old
  int xi = __builtin_bit_cast(int, x);
  int r = __builtin_amdgcn_update_dpp(xi, xi, 0x130, 0xf, 0xf, false);
  return __builtin_bit_cast(float, r);
}

// ---------------------------------------------------------------------------
// dist2: dist[b][w][lt][l][q] (fp16), q = step-in-tile; 64 halfs (128B)
// contiguous per (lane l, tile lt). Invalid cells (col out of range) = +inf.
// ---------------------------------------------------------------------------
__global__ __launch_bounds__(256)
void dist2_kernel(const float* __restrict__ obs, const float* __restrict__ mod,
                  _Float16* __restrict__ dist) {
  const int q  = threadIdx.x & 63;
  const int wv = threadIdx.x >> 6;       // 0..3
  const int lt = blockIdx.x % NTILE;
  const int lg = blockIdx.x / NTILE;     // 0..15
  const int l  = lg * 4 + wv;
  const int w  = blockIdx.y;
  const int b  = blockIdx.z;
  const int t  = lt * 64 + q;
  const int col = t - l;
  const int row = w * 64 + l;
  float dd;
  if ((unsigned)col < (unsigned)T_LEN) {
    const float4* o4 = (const float4*)(obs + ((size_t)b * T_LEN + row) * D_DIM);
    const float4* m4 = (const float4*)(mod + ((size_t)b * T_LEN + col) * D_DIM);
    float4 a0 = o4[0], a1 = o4[1], c0 = m4[0], c1 = m4[1];
    float acc = 0.f, df;
    df = a0.x - c0.x + EPSV; acc = fmaf(df, df, acc);
    df = a0.y - c0.y + EPSV; acc = fmaf(df, df, acc);
    df = a0.z - c0.z + EPSV; acc = fmaf(df, df, acc);
    df = a0.w - c0.w + EPSV; acc = fmaf(df, df, acc);
    df = a1.x - c1.x + EPSV; acc = fmaf(df, df, acc);
    df = a1.y - c1.y + EPSV; acc = fmaf(df, df, acc);
    df = a1.z - c1.z + EPSV; acc = fmaf(df, df, acc);
    df = a1.w - c1.w + EPSV; acc = fmaf(df, df, acc);
    dd = sqrtf(acc);
  } else {
    dd = __builtin_inff();
  }
  dist[(((size_t)(b * NWAVE + w) * NTILE + lt) * 64 + l) * 64 + q] = (_Float16)dd;
}

// ---------------------------------------------------------------------------
// dtw6: R6's VERIFIED dataflow; the double buffer is loaded by inline-asm
// global_load_dwordx4 (un-sinkable, forced into VGPRs) with counted
// s_waitcnt vmcnt(8) so the next tile's 8 loads stay in flight across the
// whole 64-step compute and the barrier (T3/T4 pattern).
// ---------------------------------------------------------------------------
#define GLOADO(dst, addr, OFF)                                             \
  asm volatile("global_load_dwordx4 %0, %1, off offset:" #OFF             \
               : "=v"(dst) : "v"(addr))

// one DTW step; DD = dist value (float), Q = static step-in-tile, FIX0 = (Q==0)
#define DTW_STEP(DD, Q, FIX0)                                              \
  {                                                                        \
    const float dd_ = (DD);                                                \
    float cu = dpp_shr1(c);                                                \
    float pu = dpp_shr1(p);                                                \
    cu = lane0 ? rv  : cu;                                                 \
    pu = lane0 ? rvo : pu;                                                 \
    float best = fminf(fminf(cu, pu), c);                                  \
    if (FIX0 && LT == 0) { if (w0 && lane0) best = 0.f; }                  \
    float cv = dd_ + best;                                                 \
    p = c; c = cv;                                                         \
    rvo = rv; rv = dpp_shl1(rv);                                           \
    const int t_ = T0 + (Q);                                               \
    if (lane63 && !wlast && t_ >= 63 && t_ < TSTEPS - 1)                   \
      ringbuf[w][(t_ - 63) & (RB - 1)] = c;                                \
  }

#define DTW_STEP2(U, QB)                                                   \
  {                                                                        \
    half2v hh_ = __builtin_bit_cast(half2v, (unsigned)(U));                \
    DTW_STEP((float)hh_[0], (QB), ((QB) == 0))                             \
    DTW_STEP((float)hh_[1], (QB) + 1, 0)                                   \
  }

#define DTW_STEP8(V, QB)                                                   \
  DTW_STEP2((V)[0], (QB))                                                  \
  DTW_STEP2((V)[1], (QB) + 2)                                              \
  DTW_STEP2((V)[2], (QB) + 4)                                              \
  DTW_STEP2((V)[3], (QB) + 6)

// one superstep: issue next-tile loads into N0..N7, counted-wait for the
// previous issue (feeding C0..C7), then consume C0..C7.
#define DTW_TILE(SS, C0, C1, C2, C3, C4, C5, C6, C7,                       \
                     N0, N1, N2, N3, N4, N5, N6, N7)                       \
  {                                                                        \
    const int T0 = ((SS) - 2 * w) * 64;                                    \
    if (T0 >= 0 && T0 < TSTEPS) {                                          \
      const int LT = T0 >> 6;                                              \
      if (LT < NTILE - 1) {                                                \
        const void* np_ = (const void*)(base + (size_t)(LT + 1) * 4096);   \
        GLOADO(N0, np_, 0);   GLOADO(N1, np_, 16);                         \
        GLOADO(N2, np_, 32);  GLOADO(N3, np_, 48);                         \
        GLOADO(N4, np_, 64);  GLOADO(N5, np_, 80);                         \
        GLOADO(N6, np_, 96);  GLOADO(N7, np_, 112);                        \
        asm volatile("s_waitcnt vmcnt(8)" ::: "memory");                   \
      } else {                                                             \
        asm volatile("s_waitcnt vmcnt(0)" ::: "memory");                   \
      }                                                                    \
      __builtin_amdgcn_sched_barrier(0);                                   \
      float rv, rvo;                                                       \
      if (w0) { rv = BIGV; rvo = BIGV; }                                   \
      else {                                                               \
        rv  = ringbuf[w - 1][(T0 + l) & (RB - 1)];                         \
        rvo = (LT == 0) ? BIGV : ringbuf[w - 1][(T0 - 1) & (RB - 1)];      \
      }                                                                    \
      DTW_STEP8(C0, 0)  DTW_STEP8(C1, 8)  DTW_STEP8(C2, 16)                \
      DTW_STEP8(C3, 24) DTW_STEP8(C4, 32) DTW_STEP8(C5, 40)                \
      DTW_STEP8(C6, 48) DTW_STEP8(C7, 56)                                  \
    }                                                                      \
  }

__global__ __launch_bounds__(1024)
void dtw6_kernel(const _Float16* __restrict__ dist, float* __restrict__ bres) {
  __shared__ float ringbuf[NWAVE - 1][RB];

  const int tid = threadIdx.x;
  const int b   = blockIdx.x;
  const int l   = tid & 63;
  const int w   = tid >> 6;
  const bool lane0  = (l == 0);
  const bool lane63 = (l == 63);
  const bool w0     = (w == 0);
  const bool wlast  = (w == NWAVE - 1);

  // init ring to BIGV (default for never-written entries)
  {
    float* rp = &ringbuf[0][0];
    for (int k = tid; k < (NWAVE - 1) * RB; k += 1024) rp[k] = BIGV;
  }

  const _Float16* base = dist + (size_t)(b * NWAVE + w) * NTILE * 4096 + l * 64;

  u32x4 a0, a1, a2, a3, a4, a5, a6, a7;
  u32x4 b0, b1, b2, b3, b4, b5, b6, b7;
  {
    // preload this wave's tile 0 (stays in flight; first superstep's
    // vmcnt(8) after issuing tile 1 drains it)
    const void* tp = (const void*)base;
    GLOADO(a0, tp, 0);   GLOADO(a1, tp, 16);
    GLOADO(a2, tp, 32);  GLOADO(a3, tp, 48);
    GLOADO(a4, tp, 64);  GLOADO(a5, tp, 80);
    GLOADO(a6, tp, 96);  GLOADO(a7, tp, 112);
    asm volatile("s_waitcnt vmcnt(0)" ::: "memory");
    __builtin_amdgcn_sched_barrier(0);
  }
  b0 = a0; b1 = a1; b2 = a2; b3 = a3; b4 = a4; b5 = a5; b6 = a6; b7 = a7;

  __syncthreads();   // covers ring-init

  float c = BIGV, p = BIGV;

  for (int ss = 0; ss < NSS; ss += 2) {
    DTW_TILE(ss,     a0, a1, a2, a3, a4, a5, a6, a7,
                     b0, b1, b2, b3, b4, b5, b6, b7)
    __syncthreads();
    DTW_TILE(ss + 1, b0, b1, b2, b3, b4, b5, b6, b7,
                     a0, a1, a2, a3, a4, a5, a6, a7)
    __syncthreads();
  }

  // after padded final step (t=1087, dd=inf), p holds dtw[T-1][T-1]
  if (tid == 1023) bres[b] = p;
}

// ---------------------------------------------------------------------------
// Fallback (no workspace): fused distance, per-step LDS ring (R2-verified).
// ---------------------------------------------------------------------------
__global__ __launch_bounds__(1024)
void dtw_fused_kernel(const float* __restrict__ obs, const float* __restrict__ mod,
                      float* __restrict__ bres) {
  __shared__ float ringbuf[NWAVE - 1][RB];
  __shared__ float modl[T_LEN * D_DIM];

  const int tid = threadIdx.x;
  const int b   = blockIdx.x;
  const int l   = tid & 63;
  const int w   = tid >> 6;

  const float4* msrc = (const float4*)(mod + (size_t)b * T_LEN * D_DIM);
  float4* mdst = (float4*)modl;
  mdst[tid]        = msrc[tid];
  mdst[tid + 1024] = msrc[tid + 1024];
  const float* orow = obs + ((size_t)b * T_LEN + w * 64 + l) * D_DIM;
  float4 a0 = ((const float4*)orow)[0];
  float4 a1 = ((const float4*)orow)[1];
  float obsp[8] = {a0.x + EPSV, a0.y + EPSV, a0.z + EPSV, a0.w + EPSV,
                   a1.x + EPSV, a1.y + EPSV, a1.z + EPSV, a1.w + EPSV};
  float mrow[8] = {0.f, 0.f, 0.f, 0.f, 0.f, 0.f, 0.f, 0.f};
  __syncthreads();

  float c = BIGV, p = BIGV, rprev = BIGV;
  const bool lane0  = (l == 0);
  const bool lane63 = (l == 63);
  const int  rdw    = (w > 0) ? (w - 1) : 0;
  const bool w0     = (w == 0);
  const bool wlast  = (w == NWAVE - 1);

  for (int ss = 0; ss < NSS; ++ss) {
    const int t0 = (ss - 2 * w) * 64;
    if (t0 >= 0 && t0 < TSTEPS) {
#pragma unroll 8
      for (int q = 0; q < 64; ++q) {
        const int t = t0 + q;
#pragma unroll
        for (int d = 0; d < 8; ++d) mrow[d] = dpp_shr1(mrow[d]);
        if (lane0) {
          const int tm = (t < T_LEN) ? t : (T_LEN - 1);
          const float4* mr = (const float4*)(modl + tm * 8);
          float4 m0 = mr[0], m1 = mr[1];
          mrow[0] = m0.x; mrow[1] = m0.y; mrow[2] = m0.z; mrow[3] = m0.w;
          mrow[4] = m1.x; mrow[5] = m1.y; mrow[6] = m1.z; mrow[7] = m1.w;
        }
        float acc = 0.f;
#pragma unroll
        for (int d = 0; d < 8; ++d) { float df = obsp[d] - mrow[d]; acc = fmaf(df, df, acc); }
        float dd = sqrtf(acc);

        float c_up = dpp_shr1(c);
        float p_up = dpp_shr1(p);
        float ringv = ringbuf[rdw][t & (RB - 1)];
        if (lane0) { c_up = w0 ? BIGV : ringv; p_up = w0 ? BIGV : rprev; }
        rprev = ringv;

        const int j = t - l;
        const bool valid = ((unsigned)j < (unsigned)T_LEN);
        float best = fminf(fminf(c_up, p_up), c);
        if (w0 && t == 0) { if (lane0) best = 0.f; }
        float cur = valid ? (dd + best) : BIGV;
        p = c; c = cur;

        if (lane63 && !wlast && t >= 63 && t < TSTEPS - 1)
          ringbuf[w][(t - 63) & (RB - 1)] = c;
      }
    }
    __syncthreads();
  }
  if (tid == 1023) bres[b] = p;
}

__global__ void mean_kernel(const float* __restrict__ bres, float* __restrict__ out, int B) {
  if (threadIdx.x == 0) {
    float s = 0.f;
    for (int i = 0; i < B; ++i) s += bres[i];
    out[0] = s / (float)B;
  }
}

extern "C" void kernel_launch(void* const* d_in, const int* in_sizes, int n_in,
                              void* d_out, int out_size, void* d_ws, size_t ws_size,
                              hipStream_t stream) {
  (void)n_in; (void)out_size;
  const float* obs = (const float*)d_in[0];
  const float* mod = (const float*)d_in[1];
  float* out = (float*)d_out;
  const int B = in_sizes[0] / (T_LEN * D_DIM);

  float* bres = (float*)d_ws;                            // B floats
  _Float16* dist = (_Float16*)((char*)d_ws + 256);       // dist scratch
  const size_t need = 256 + (size_t)B * NWAVE * NTILE * 64 * 64 * sizeof(_Float16);

  if (ws_size >= need) {
    dist2_kernel<<<dim3(NTILE * 16, NWAVE, B), 256, 0, stream>>>(obs, mod, dist);
    dtw6_kernel<<<B, 1024, 0, stream>>>(dist, bres);
  } else {
    dtw_fused_kernel<<<B, 1024, 0, stream>>>(obs, mod, bres);
  }
  mean_kernel<<<1, 64, 0, stream>>>(bres, out, B);
}

// Round 8
// 134.381 us; speedup vs baseline: 7.0259x; 1.6607x over previous
//
#include <hip/hip_runtime.h>

#define T_LEN  1024
#define D_DIM  8
#define NWAVE  16          // waves per DTW block = T/64
#define NTILE  17          // 64-step tiles per wave (1088 local steps)
#define TSTEPS 1088
#define RB     256         // ring entries (power of 2)
#define NSS    47          // 2*(NWAVE-1) + NTILE super-steps
#define BIGV   1e30f
#define EPSV   1e-6f

typedef _Float16 half2v __attribute__((ext_vector_type(2)));
typedef unsigned u32x4  __attribute__((ext_vector_type(4)));

__device__ __forceinline__ float dpp_shr1(float x) {   // dst[n] = src[n-1]; lane0 keeps old
  int xi = __builtin_bit_cast(int, x);
  int r = __builtin_amdgcn_update_dpp(xi, xi, 0x138, 0xf, 0xf, false);
  return __builtin_bit_cast(float, r);
}
__device__ __forceinline__ float dpp_shl1(float x) {   // dst[n] = src[n+1]; lane63 keeps old
  int xi = __builtin_bit_cast(int, x);
  int r = __builtin_amdgcn_update_dpp(xi, xi, 0x130, 0xf, 0xf, false);
  return __builtin_bit_cast(float, r);
}

// ---------------------------------------------------------------------------
// dist2: dist[b][w][lt][l][q] (fp16), q = step-in-tile; 64 halfs (128B)
// contiguous per (lane l, tile lt). Invalid cells (col out of range) = +inf.
// ---------------------------------------------------------------------------
__global__ __launch_bounds__(256)
void dist2_kernel(const float* __restrict__ obs, const float* __restrict__ mod,
                  _Float16* __restrict__ dist) {
  const int q  = threadIdx.x & 63;
  const int wv = threadIdx.x >> 6;       // 0..3
  const int lt = blockIdx.x % NTILE;
  const int lg = blockIdx.x / NTILE;     // 0..15
  const int l  = lg * 4 + wv;
  const int w  = blockIdx.y;
  const int b  = blockIdx.z;
  const int t  = lt * 64 + q;
  const int col = t - l;
  const int row = w * 64 + l;
  float dd;
  if ((unsigned)col < (unsigned)T_LEN) {
    const float4* o4 = (const float4*)(obs + ((size_t)b * T_LEN + row) * D_DIM);
    const float4* m4 = (const float4*)(mod + ((size_t)b * T_LEN + col) * D_DIM);
    float4 a0 = o4[0], a1 = o4[1], c0 = m4[0], c1 = m4[1];
    float acc = 0.f, df;
    df = a0.x - c0.x + EPSV; acc = fmaf(df, df, acc);
    df = a0.y - c0.y + EPSV; acc = fmaf(df, df, acc);
    df = a0.z - c0.z + EPSV; acc = fmaf(df, df, acc);
    df = a0.w - c0.w + EPSV; acc = fmaf(df, df, acc);
    df = a1.x - c1.x + EPSV; acc = fmaf(df, df, acc);
    df = a1.y - c1.y + EPSV; acc = fmaf(df, df, acc);
    df = a1.z - c1.z + EPSV; acc = fmaf(df, df, acc);
    df = a1.w - c1.w + EPSV; acc = fmaf(df, df, acc);
    dd = sqrtf(acc);
  } else {
    dd = __builtin_inff();
  }
  dist[(((size_t)(b * NWAVE + w) * NTILE + lt) * 64 + l) * 64 + q] = (_Float16)dd;
}

// ---------------------------------------------------------------------------
// dtw7: R7's VERIFIED dataflow; the per-step lane63 ds_write is replaced by
// a register collect (dpp_shl + cndmask per step) and ONE lane-predicated
// coalesced LDS write per superstep.
//   - producer (wave w, superstep for tile T0) writes entries [T0-63, T0]
//     clamped to [0,1023]; lane l holds entry T0-63+l after the collect.
//   - same-superstep consumer (wave w+1) reads entries [T0-129, T0-65]:
//     disjoint; total span 130 < 256 so no mod-256 aliasing. Cross-superstep
//     ordering via the existing __syncthreads().
// ---------------------------------------------------------------------------
#define GLOADO(dst, addr, OFF)                                             \
  asm volatile("global_load_dwordx4 %0, %1, off offset:" #OFF             \
               : "=v"(dst) : "v"(addr))

// one DTW step; DD = dist value (float), Q = static step-in-tile, FIX0 = (Q==0)
#define DTW_STEP(DD, Q, FIX0)                                              \
  {                                                                        \
    const float dd_ = (DD);                                                \
    float cu = dpp_shr1(c);                                                \
    float pu = dpp_shr1(p);                                                \
    cu = lane0 ? rv  : cu;                                                 \
    pu = lane0 ? rvo : pu;                                                 \
    float best = fminf(fminf(cu, pu), c);                                  \
    if (FIX0 && LT == 0) { if (w0 && lane0) best = 0.f; }                  \
    float cv = dd_ + best;                                                 \
    p = c; c = cv;                                                         \
    rvo = rv; rv = dpp_shl1(rv);                                           \
    out = dpp_shl1(out);                                                   \
    out = lane63 ? c : out;                                                \
  }

#define DTW_STEP2(U, QB)                                                   \
  {                                                                        \
    half2v hh_ = __builtin_bit_cast(half2v, (unsigned)(U));                \
    DTW_STEP((float)hh_[0], (QB), ((QB) == 0))                             \
    DTW_STEP((float)hh_[1], (QB) + 1, 0)                                   \
  }

#define DTW_STEP8(V, QB)                                                   \
  DTW_STEP2((V)[0], (QB))                                                  \
  DTW_STEP2((V)[1], (QB) + 2)                                              \
  DTW_STEP2((V)[2], (QB) + 4)                                              \
  DTW_STEP2((V)[3], (QB) + 6)

// one superstep: issue next-tile loads into N0..N7, counted-wait for the
// previous issue (feeding C0..C7), consume C0..C7, then publish boundary.
#define DTW_TILE(SS, C0, C1, C2, C3, C4, C5, C6, C7,                       \
                     N0, N1, N2, N3, N4, N5, N6, N7)                       \
  {                                                                        \
    const int T0 = ((SS) - 2 * w) * 64;                                    \
    if (T0 >= 0 && T0 < TSTEPS) {                                          \
      const int LT = T0 >> 6;                                              \
      if (LT < NTILE - 1) {                                                \
        const void* np_ = (const void*)(base + (size_t)(LT + 1) * 4096);   \
        GLOADO(N0, np_, 0);   GLOADO(N1, np_, 16);                         \
        GLOADO(N2, np_, 32);  GLOADO(N3, np_, 48);                         \
        GLOADO(N4, np_, 64);  GLOADO(N5, np_, 80);                         \
        GLOADO(N6, np_, 96);  GLOADO(N7, np_, 112);                        \
        asm volatile("s_waitcnt vmcnt(8)" ::: "memory");                   \
      } else {                                                             \
        asm volatile("s_waitcnt vmcnt(0)" ::: "memory");                   \
      }                                                                    \
      __builtin_amdgcn_sched_barrier(0);                                   \
      float rv, rvo;                                                       \
      if (w0) { rv = BIGV; rvo = BIGV; }                                   \
      else {                                                               \
        rv  = ringbuf[w - 1][(T0 + l) & (RB - 1)];                         \
        rvo = (LT == 0) ? BIGV : ringbuf[w - 1][(T0 - 1) & (RB - 1)];      \
      }                                                                    \
      float out = 0.f;                                                     \
      DTW_STEP8(C0, 0)  DTW_STEP8(C1, 8)  DTW_STEP8(C2, 16)                \
      DTW_STEP8(C3, 24) DTW_STEP8(C4, 32) DTW_STEP8(C5, 40)                \
      DTW_STEP8(C6, 48) DTW_STEP8(C7, 56)                                  \
      if (!wlast) {                                                        \
        const int e_ = T0 - 63 + l;                                        \
        if ((unsigned)e_ < (unsigned)T_LEN)                                \
          ringbuf[w][e_ & (RB - 1)] = out;                                 \
      }                                                                    \
    }                                                                      \
  }

__global__ __launch_bounds__(1024)
void dtw7_kernel(const _Float16* __restrict__ dist, float* __restrict__ bres) {
  __shared__ float ringbuf[NWAVE - 1][RB];

  const int tid = threadIdx.x;
  const int b   = blockIdx.x;
  const int l   = tid & 63;
  const int w   = tid >> 6;
  const bool lane0  = (l == 0);
  const bool lane63 = (l == 63);
  const bool w0     = (w == 0);
  const bool wlast  = (w == NWAVE - 1);

  // init ring to BIGV (safety default; all consumed entries are also written)
  {
    float* rp = &ringbuf[0][0];
    for (int k = tid; k < (NWAVE - 1) * RB; k += 1024) rp[k] = BIGV;
  }

  const _Float16* base = dist + (size_t)(b * NWAVE + w) * NTILE * 4096 + l * 64;

  u32x4 a0, a1, a2, a3, a4, a5, a6, a7;
  u32x4 b0, b1, b2, b3, b4, b5, b6, b7;
  {
    const void* tp = (const void*)base;   // this wave's tile 0
    GLOADO(a0, tp, 0);   GLOADO(a1, tp, 16);
    GLOADO(a2, tp, 32);  GLOADO(a3, tp, 48);
    GLOADO(a4, tp, 64);  GLOADO(a5, tp, 80);
    GLOADO(a6, tp, 96);  GLOADO(a7, tp, 112);
    asm volatile("s_waitcnt vmcnt(0)" ::: "memory");
    __builtin_amdgcn_sched_barrier(0);
  }
  b0 = a0; b1 = a1; b2 = a2; b3 = a3; b4 = a4; b5 = a5; b6 = a6; b7 = a7;

  __syncthreads();   // covers ring-init

  float c = BIGV, p = BIGV;

  for (int ss = 0; ss < NSS; ss += 2) {
    DTW_TILE(ss,     a0, a1, a2, a3, a4, a5, a6, a7,
                     b0, b1, b2, b3, b4, b5, b6, b7)
    __syncthreads();
    DTW_TILE(ss + 1, b0, b1, b2, b3, b4, b5, b6, b7,
                     a0, a1, a2, a3, a4, a5, a6, a7)
    __syncthreads();
  }

  // after padded final step (t=1087, dd=inf), p holds dtw[T-1][T-1]
  if (tid == 1023) bres[b] = p;
}

// ---------------------------------------------------------------------------
// Fallback (no workspace): fused distance, per-step LDS ring (R2-verified).
// ---------------------------------------------------------------------------
__global__ __launch_bounds__(1024)
void dtw_fused_kernel(const float* __restrict__ obs, const float* __restrict__ mod,
                      float* __restrict__ bres) {
  __shared__ float ringbuf[NWAVE - 1][RB];
  __shared__ float modl[T_LEN * D_DIM];

  const int tid = threadIdx.x;
  const int b   = blockIdx.x;
  const int l   = tid & 63;
  const int w   = tid >> 6;

  const float4* msrc = (const float4*)(mod + (size_t)b * T_LEN * D_DIM);
  float4* mdst = (float4*)modl;
  mdst[tid]        = msrc[tid];
  mdst[tid + 1024] = msrc[tid + 1024];
  const float* orow = obs + ((size_t)b * T_LEN + w * 64 + l) * D_DIM;
  float4 a0 = ((const float4*)orow)[0];
  float4 a1 = ((const float4*)orow)[1];
  float obsp[8] = {a0.x + EPSV, a0.y + EPSV, a0.z + EPSV, a0.w + EPSV,
                   a1.x + EPSV, a1.y + EPSV, a1.z + EPSV, a1.w + EPSV};
  float mrow[8] = {0.f, 0.f, 0.f, 0.f, 0.f, 0.f, 0.f, 0.f};
  __syncthreads();

  float c = BIGV, p = BIGV, rprev = BIGV;
  const bool lane0  = (l == 0);
  const bool lane63 = (l == 63);
  const int  rdw    = (w > 0) ? (w - 1) : 0;
  const bool w0     = (w == 0);
  const bool wlast  = (w == NWAVE - 1);

  for (int ss = 0; ss < NSS; ++ss) {
    const int t0 = (ss - 2 * w) * 64;
    if (t0 >= 0 && t0 < TSTEPS) {
#pragma unroll 8
      for (int q = 0; q < 64; ++q) {
        const int t = t0 + q;
#pragma unroll
        for (int d = 0; d < 8; ++d) mrow[d] = dpp_shr1(mrow[d]);
        if (lane0) {
          const int tm = (t < T_LEN) ? t : (T_LEN - 1);
          const float4* mr = (const float4*)(modl + tm * 8);
          float4 m0 = mr[0], m1 = mr[1];
          mrow[0] = m0.x; mrow[1] = m0.y; mrow[2] = m0.z; mrow[3] = m0.w;
          mrow[4] = m1.x; mrow[5] = m1.y; mrow[6] = m1.z; mrow[7] = m1.w;
        }
        float acc = 0.f;
#pragma unroll
        for (int d = 0; d < 8; ++d) { float df = obsp[d] - mrow[d]; acc = fmaf(df, df, acc); }
        float dd = sqrtf(acc);

        float c_up = dpp_shr1(c);
        float p_up = dpp_shr1(p);
        float ringv = ringbuf[rdw][t & (RB - 1)];
        if (lane0) { c_up = w0 ? BIGV : ringv; p_up = w0 ? BIGV : rprev; }
        rprev = ringv;

        const int j = t - l;
        const bool valid = ((unsigned)j < (unsigned)T_LEN);
        float best = fminf(fminf(c_up, p_up), c);
        if (w0 && t == 0) { if (lane0) best = 0.f; }
        float cur = valid ? (dd + best) : BIGV;
        p = c; c = cur;

        if (lane63 && !wlast && t >= 63 && t < TSTEPS - 1)
          ringbuf[w][(t - 63) & (RB - 1)] = c;
      }
    }
    __syncthreads();
  }
  if (tid == 1023) bres[b] = p;
}

__global__ void mean_kernel(const float* __restrict__ bres, float* __restrict__ out, int B) {
  if (threadIdx.x == 0) {
    float s = 0.f;
    for (int i = 0; i < B; ++i) s += bres[i];
    out[0] = s / (float)B;
  }
}

extern "C" void kernel_launch(void* const* d_in, const int* in_sizes, int n_in,
                              void* d_out, int out_size, void* d_ws, size_t ws_size,
                              hipStream_t stream) {
  (void)n_in; (void)out_size;
  const float* obs = (const float*)d_in[0];
  const float* mod = (const float*)d_in[1];
  float* out = (float*)d_out;
  const int B = in_sizes[0] / (T_LEN * D_DIM);

  float* bres = (float*)d_ws;                            // B floats
  _Float16* dist = (_Float16*)((char*)d_ws + 256);       // dist scratch
  const size_t need = 256 + (size_t)B * NWAVE * NTILE * 64 * 64 * sizeof(_Float16);

  if (ws_size >= need) {
    dist2_kernel<<<dim3(NTILE * 16, NWAVE, B), 256, 0, stream>>>(obs, mod, dist);
    dtw7_kernel<<<B, 1024, 0, stream>>>(dist, bres);
  } else {
    dtw_fused_kernel<<<B, 1024, 0, stream>>>(obs, mod, bres);
  }
  mean_kernel<<<1, 64, 0, stream>>>(bres, out, B);
}